// Round 18
// baseline (596.501 us; speedup 1.0000x reference)
//
#include <hip/hip_runtime.h>

#define Bb 8
#define Nn 2048
#define Dd 512

#define KV 32            // keys per tile/image
#define NT 64            // images per batch
#define PPS 42           // sP row stride (u16 elements)

// fallback (no ws): R10 structure
#define KVF 64
#define NTF (Nn / KVF)
#define PPF 72

typedef __attribute__((ext_vector_type(8))) short bf8;
typedef __attribute__((ext_vector_type(4))) float f4;
struct __align__(16) U8 { unsigned short s[8]; };

__device__ __forceinline__ unsigned short f2bf(float f) {
  union { float f; unsigned u; } v; v.f = f;
  unsigned r = v.u + 0x7fffu + ((v.u >> 16) & 1u);
  return (unsigned short)(r >> 16);
}

// ---------------------------------------------------------------------------
// Build per-(b,tile) images in ws, once.  Image = [K 16384 | Vt 16384] u16.
//   K : key*512 + ((c ^ (key&7))<<3), c = d>>3        (LDS-swizzled row-major)
//   Vt: 16384 + d*32 + ((g ^ ((d>>1)&3))<<3), g = key>>3  (transpose)
// ---------------------------------------------------------------------------
__global__ __launch_bounds__(256)
void build_images(const float* __restrict__ X, unsigned short* __restrict__ W) {
  __shared__ float sT[KV * Dd];  // 64 KB
  const int t = blockIdx.x, b = blockIdx.y, tid = threadIdx.x;
  const float* src = X + ((size_t)b * Nn + t * KV) * Dd;
#pragma unroll
  for (int i = 0; i < 16; ++i) {
    int idx = i * 256 + tid;
    *(float4*)(sT + idx * 4) = *(const float4*)(src + idx * 4);
  }
  __syncthreads();
  unsigned short* img = W + ((size_t)(b * NT + t) << 15);
#pragma unroll
  for (int i = 0; i < 8; ++i) {
    int idx = i * 256 + tid;
    int key = idx >> 6, c = idx & 63;
    const float* p = sT + key * Dd + c * 8;
    U8 v;
#pragma unroll
    for (int j = 0; j < 8; ++j) v.s[j] = f2bf(p[j]);
    *(U8*)(img + key * 512 + ((c ^ (key & 7)) << 3)) = v;
  }
#pragma unroll
  for (int i = 0; i < 8; ++i) {
    int idx = i * 256 + tid;
    int d = idx >> 2, g = idx & 3;
    U8 v;
#pragma unroll
    for (int e = 0; e < 8; ++e) v.s[e] = f2bf(sT[(g * 8 + e) * Dd + d]);
    *(U8*)(img + 16384 + d * 32 + ((g ^ ((d >> 1) & 3)) << 3)) = v;
  }
}

// ---------------------------------------------------------------------------
// D-split attention, LDS-aliased exchange. 512 thr = 8 waves = 2qg x 4dw.
// Wave (qg,dw): 16 q-rows, d-quarter [dw*128, +128).
// LDS = sK 32 KB (bytes [0,16K) reused as f32 partial-S exchange between
// barA..barC) + sP 2.6 KB = 34.9 KB -> 2 blocks/CU (proven at <=37.9 KB),
// 16 waves/CU = 4 waves/SIMD, single pass over the 512-block grid.
// Tile: prefetch K(regs); QK^T; barA; partials->sK[0:16K) + Khalf2->sK[16K:32K);
// barB; fixed-order f32 sum + softmax + P; barC; Khalf1->sK[0:16K); PV(L2); barD.
// ---------------------------------------------------------------------------
__global__ __launch_bounds__(512, 1)
void attn_ds2(const unsigned short* __restrict__ W, const int* __restrict__ mask,
              float* __restrict__ out) {
  __shared__ unsigned short sK[16384];        // 32 KB (front 16 KB aliased)
  __shared__ unsigned short sP[2][16 * PPS];  // 2.6 KB

  const int tid  = threadIdx.x;
  const int wave = tid >> 6;
  const int qg = wave >> 2, dw = wave & 3;
  const int lane = tid & 63;
  const int lg = lane >> 4, ll = lane & 15;
  const int slot = lg * 16 + ll;              // 0..63
  const int bid = blockIdx.x;
  const int b = bid & 7;                      // XCD-batch affinity
  const int qb = bid >> 3;                    // 0..63
  const int q0 = qb * 32 + qg * 16;
  const int bN = b * NT;
  const float scale = 0.044194173824159216f;  // 1/sqrt(512)

  f4* sS = (f4*)sK;                           // [2][4][2][64] f4 = 16 KB alias

  // Q fragments for this wave's d-quarter (from the K-images, same addr math)
  bf8 qf[4];
  {
    int qrow = q0 + ll;
    const unsigned short* qimg = W + ((size_t)(bN + (qrow >> 5)) << 15);
    int qk = qrow & 31;
#pragma unroll
    for (int ch = 0; ch < 4; ++ch) {
      int c = dw * 16 + ch * 4 + lg;
      qf[ch] = *(const bf8*)(qimg + qk * 512 + ((c ^ (qk & 7)) << 3));
    }
  }

  float bias[4];
#pragma unroll
  for (int r = 0; r < 4; ++r)
    bias[r] = (1.0f - (float)mask[b * Nn + q0 + lg * 4 + r]) * 1e9f;

  float m[4], lsum[4];
  f4 o[8];
#pragma unroll
  for (int r = 0; r < 4; ++r) { m[r] = -1e30f; lsum[r] = 0.0f; }
#pragma unroll
  for (int ct = 0; ct < 8; ++ct) o[ct] = (f4){0.f, 0.f, 0.f, 0.f};

  // prologue: stage K tile 0 (32 KB = 4 x 16B per thread)
  {
    const unsigned short* img0 = W + ((size_t)bN << 15);
#pragma unroll
    for (int i = 0; i < 4; ++i)
      *(U8*)(sK + (i * 512 + tid) * 8) = *(const U8*)(img0 + (i * 512 + tid) * 8);
  }
  __syncthreads();

  for (int t = 0; t < NT; ++t) {
    const bool pf = (t + 1 < NT);
    const unsigned short* gKn = W + ((size_t)(bN + t + 1) << 15);

    // prefetch next K tile into registers (2 halves x 2 chunks)
    U8 stA[2], stB[2];
    if (pf) {
#pragma unroll
      for (int i = 0; i < 2; ++i) {
        stA[i] = *(const U8*)(gKn + ((i * 512 + tid)) * 8);          // bytes [0,16K)
        stB[i] = *(const U8*)(gKn + ((1024 + i * 512 + tid)) * 8);   // bytes [16K,32K)
      }
    }

    // ---- QK^T partial over d-quarter: 8 MFMAs ----
    f4 s2[2];
    s2[0] = (f4){0.f, 0.f, 0.f, 0.f};
    s2[1] = (f4){0.f, 0.f, 0.f, 0.f};
#pragma unroll
    for (int ch = 0; ch < 4; ++ch) {
#pragma unroll
      for (int cc = 0; cc < 2; ++cc) {
        int key = cc * 16 + ll;
        int c = dw * 16 + ch * 4 + lg;
        bf8 kf = *(const bf8*)(sK + key * 512 + ((c ^ (key & 7)) << 3));
        s2[cc] = __builtin_amdgcn_mfma_f32_16x16x32_bf16(qf[ch], kf, s2[cc], 0, 0, 0);
      }
    }
    __syncthreads();  // barA: all K reads done -> front 16 KB reusable

    // write partial S into the alias region; write next-K half2 (back 16 KB)
    sS[((qg * 4 + dw) * 2 + 0) * 64 + slot] = s2[0];
    sS[((qg * 4 + dw) * 2 + 1) * 64 + slot] = s2[1];
    if (pf) {
#pragma unroll
      for (int i = 0; i < 2; ++i)
        *(U8*)(sK + (1024 + i * 512 + tid) * 8) = stB[i];
    }
    __syncthreads();  // barB: partials visible

    // ---- fixed-order full-D sum (identical in all dw waves) ----
    f4 sum0 = ((sS[(qg * 4 + 0) * 2 * 64 + slot] + sS[(qg * 4 + 1) * 2 * 64 + slot]) +
               sS[(qg * 4 + 2) * 2 * 64 + slot]) + sS[(qg * 4 + 3) * 2 * 64 + slot];
    f4 sum1 = ((sS[((qg * 4 + 0) * 2 + 1) * 64 + slot] + sS[((qg * 4 + 1) * 2 + 1) * 64 + slot]) +
               sS[((qg * 4 + 2) * 2 + 1) * 64 + slot]) + sS[((qg * 4 + 3) * 2 + 1) * 64 + slot];

    float e2[2][4];
#pragma unroll
    for (int r = 0; r < 4; ++r) {
      e2[0][r] = sum0[r] * scale - bias[r];   // f32: masked rows -> exactly -1e9
      e2[1][r] = sum1[r] * scale - bias[r];
    }

    // ---- online softmax (replicated across dw; identical results) ----
    float tm[4];
#pragma unroll
    for (int r = 0; r < 4; ++r) tm[r] = fmaxf(e2[0][r], e2[1][r]);
#pragma unroll
    for (int off = 1; off < 16; off <<= 1)
#pragma unroll
      for (int r = 0; r < 4; ++r) tm[r] = fmaxf(tm[r], __shfl_xor(tm[r], off));

    float mn[4];
    bool change = false;
#pragma unroll
    for (int r = 0; r < 4; ++r) { mn[r] = fmaxf(m[r], tm[r]); change = change || (mn[r] > m[r]); }
    if (__any(change)) {
#pragma unroll
      for (int r = 0; r < 4; ++r) {
        float al = __expf(m[r] - mn[r]);
        lsum[r] *= al;
        m[r] = mn[r];
#pragma unroll
        for (int ct = 0; ct < 8; ++ct) o[ct][r] *= al;
      }
    }

    float ts[4] = {0.f, 0.f, 0.f, 0.f};
    unsigned short pb[2][4];
#pragma unroll
    for (int cc = 0; cc < 2; ++cc)
#pragma unroll
      for (int r = 0; r < 4; ++r) {
        float p = __expf(e2[cc][r] - m[r]);
        ts[r] += p;
        pb[cc][r] = f2bf(p);
      }
#pragma unroll
    for (int off = 1; off < 16; off <<= 1)
#pragma unroll
      for (int r = 0; r < 4; ++r) ts[r] += __shfl_xor(ts[r], off);
#pragma unroll
    for (int r = 0; r < 4; ++r) lsum[r] += ts[r];

    // ---- shared P (each wave writes the full 16x32 P for its qg; all dw
    //      waves write bit-identical bytes; af read is same-wave ordered) ----
    unsigned short* Pw = sP[qg];
#pragma unroll
    for (int cc = 0; cc < 2; ++cc)
#pragma unroll
      for (int r = 0; r < 4; ++r)
        Pw[(lg * 4 + r) * PPS + cc * 16 + ll] = pb[cc][r];
    bf8 af = *(const bf8*)(Pw + ll * PPS + lg * 8);

    __syncthreads();  // barC: all alias-region reads done

    // write next-K half1 into the (now free) front 16 KB
    if (pf) {
#pragma unroll
      for (int i = 0; i < 2; ++i)
        *(U8*)(sK + (i * 512 + tid) * 8) = stA[i];
    }

    // ---- PV: this wave's d-quarter of V straight from L2 ----
    const unsigned short* gV = W + ((size_t)(bN + t) << 15) + 16384;
    bf8 va[4];
#pragma unroll
    for (int g = 0; g < 2; ++g) {
#pragma unroll
      for (int j = 0; j < 4; ++j) {
        int ct = g * 4 + j;
        int d = dw * 128 + ct * 16 + ll;
        va[j] = *(const bf8*)(gV + d * 32 + ((lg ^ ((d >> 1) & 3)) << 3));
      }
#pragma unroll
      for (int j = 0; j < 4; ++j)
        o[g * 4 + j] = __builtin_amdgcn_mfma_f32_16x16x32_bf16(af, va[j], o[g * 4 + j], 0, 0, 0);
    }
    __syncthreads();  // barD: K writes settled before next QK^T
  }

  // ---- epilogue: normalize, store this wave's 16q x 128d block ----
  float inv[4];
#pragma unroll
  for (int r = 0; r < 4; ++r) inv[r] = 1.0f / lsum[r];
#pragma unroll
  for (int ct = 0; ct < 8; ++ct)
#pragma unroll
    for (int r = 0; r < 4; ++r) {
      size_t row = (size_t)b * Nn + q0 + lg * 4 + r;
      out[row * Dd + dw * 128 + ct * 16 + ll] = o[ct][r] * inv[r];
    }
}

// ---------------------------------------------------------------------------
// Fallback (no usable ws): R10 structure, KV=64, in-kernel convert.
// ---------------------------------------------------------------------------
__global__ __launch_bounds__(256, 1)
void attn_fb(const float* __restrict__ Xf, const int* __restrict__ mask,
             float* __restrict__ out) {
  __shared__ unsigned short sKf[KVF * Dd];
  __shared__ unsigned short sVt[Dd * KVF];
  __shared__ unsigned short sPf[4][16 * PPF];

  const int tid  = threadIdx.x;
  const int wave = tid >> 6, lane = tid & 63;
  const int lg = lane >> 4, ll = lane & 15;
  const int b  = blockIdx.y;
  const int q0 = blockIdx.x * 64 + wave * 16;

  bf8 qf[16];
  {
    const size_t qoff = ((size_t)b * Nn + q0 + ll) * Dd;
#pragma unroll
    for (int ch = 0; ch < 16; ++ch) {
      int doff = ch * 32 + lg * 8;
      float4 a = *(const float4*)(Xf + qoff + doff);
      float4 c = *(const float4*)(Xf + qoff + doff + 4);
      bf8 tt;
      tt[0] = (short)f2bf(a.x); tt[1] = (short)f2bf(a.y);
      tt[2] = (short)f2bf(a.z); tt[3] = (short)f2bf(a.w);
      tt[4] = (short)f2bf(c.x); tt[5] = (short)f2bf(c.y);
      tt[6] = (short)f2bf(c.z); tt[7] = (short)f2bf(c.w);
      qf[ch] = tt;
    }
  }
  float bias[4];
#pragma unroll
  for (int r = 0; r < 4; ++r)
    bias[r] = (1.0f - (float)mask[b * Nn + q0 + lg * 4 + r]) * 1e9f;
  float m[4], lsum[4];
  f4 o[32];
#pragma unroll
  for (int r = 0; r < 4; ++r) { m[r] = -1e30f; lsum[r] = 0.0f; }
#pragma unroll
  for (int ct = 0; ct < 32; ++ct) o[ct] = (f4){0.f, 0.f, 0.f, 0.f};
  const float scale = 0.044194173824159216f;

  for (int t = 0; t < NTF; ++t) {
    __syncthreads();
    const size_t base = ((size_t)b * Nn + t * KVF) * Dd;
#pragma unroll
    for (int it = 0; it < 16; ++it) {
      int idx = it * 256 + tid;
      int key = idx >> 6, c = idx & 63;
      const float* sp = Xf + base + key * Dd + c * 8;
      float4 a = *(const float4*)(sp);
      float4 d2 = *(const float4*)(sp + 4);
      U8 v;
      v.s[0] = f2bf(a.x); v.s[1] = f2bf(a.y); v.s[2] = f2bf(a.z); v.s[3] = f2bf(a.w);
      v.s[4] = f2bf(d2.x); v.s[5] = f2bf(d2.y); v.s[6] = f2bf(d2.z); v.s[7] = f2bf(d2.w);
      *(U8*)(sKf + key * 512 + ((c ^ (key & 7)) << 3)) = v;
      int ko = key >> 3, k7 = key & 7;
#pragma unroll
      for (int j = 0; j < 8; ++j) {
        int dd = c * 8 + j;
        sVt[dd * 64 + ((ko ^ j ^ (c & 7)) << 3) + k7] = v.s[j];
      }
    }
    __syncthreads();

    f4 s[4];
#pragma unroll
    for (int cc = 0; cc < 4; ++cc) s[cc] = (f4){0.f, 0.f, 0.f, 0.f};
#pragma unroll
    for (int ch = 0; ch < 16; ++ch)
#pragma unroll
      for (int cc = 0; cc < 4; ++cc) {
        int key = cc * 16 + ll;
        bf8 kf = *(const bf8*)(sKf + key * 512 + (((ch * 4 + lg) ^ (key & 7)) << 3));
        s[cc] = __builtin_amdgcn_mfma_f32_16x16x32_bf16(qf[ch], kf, s[cc], 0, 0, 0);
      }

    float e[4][4];
#pragma unroll
    for (int cc = 0; cc < 4; ++cc)
#pragma unroll
      for (int r = 0; r < 4; ++r) e[cc][r] = s[cc][r] * scale - bias[r];
    float tm[4];
#pragma unroll
    for (int r = 0; r < 4; ++r)
      tm[r] = fmaxf(fmaxf(e[0][r], e[1][r]), fmaxf(e[2][r], e[3][r]));
#pragma unroll
    for (int off = 1; off < 16; off <<= 1)
#pragma unroll
      for (int r = 0; r < 4; ++r) tm[r] = fmaxf(tm[r], __shfl_xor(tm[r], off));
    float mn[4]; bool change = false;
#pragma unroll
    for (int r = 0; r < 4; ++r) { mn[r] = fmaxf(m[r], tm[r]); change = change || (mn[r] > m[r]); }
    if (__any(change)) {
#pragma unroll
      for (int r = 0; r < 4; ++r) {
        float al = __expf(m[r] - mn[r]);
        lsum[r] *= al; m[r] = mn[r];
#pragma unroll
        for (int ct = 0; ct < 32; ++ct) o[ct][r] *= al;
      }
    }
    float ts[4] = {0.f, 0.f, 0.f, 0.f};
    unsigned short pb[4][4];
#pragma unroll
    for (int cc = 0; cc < 4; ++cc)
#pragma unroll
      for (int r = 0; r < 4; ++r) {
        float p = __expf(e[cc][r] - m[r]);
        ts[r] += p; pb[cc][r] = f2bf(p);
      }
#pragma unroll
    for (int off = 1; off < 16; off <<= 1)
#pragma unroll
      for (int r = 0; r < 4; ++r) ts[r] += __shfl_xor(ts[r], off);
#pragma unroll
    for (int r = 0; r < 4; ++r) lsum[r] += ts[r];

    unsigned short* Pw = sPf[wave];
#pragma unroll
    for (int cc = 0; cc < 4; ++cc)
#pragma unroll
      for (int r = 0; r < 4; ++r)
        Pw[(lg * 4 + r) * PPF + cc * 16 + ll] = pb[cc][r];
#pragma unroll
    for (int kc = 0; kc < 2; ++kc) {
      bf8 af = *(const bf8*)(Pw + ll * PPF + kc * 32 + lg * 8);
#pragma unroll
      for (int ct = 0; ct < 32; ++ct) {
        int d = ct * 16 + ll;
        bf8 vf = *(const bf8*)(sVt + d * 64 + (((kc * 4 + lg) ^ (d & 7) ^ ((d >> 3) & 7)) << 3));
        o[ct] = __builtin_amdgcn_mfma_f32_16x16x32_bf16(af, vf, o[ct], 0, 0, 0);
      }
    }
  }
  float inv[4];
#pragma unroll
  for (int r = 0; r < 4; ++r) inv[r] = 1.0f / lsum[r];
#pragma unroll
  for (int ct = 0; ct < 32; ++ct)
#pragma unroll
    for (int r = 0; r < 4; ++r) {
      size_t row = (size_t)b * Nn + q0 + lg * 4 + r;
      out[row * Dd + ct * 16 + ll] = o[ct][r] * inv[r];
    }
}

extern "C" void kernel_launch(void* const* d_in, const int* in_sizes, int n_in,
                              void* d_out, int out_size, void* d_ws, size_t ws_size,
                              hipStream_t stream) {
  (void)in_sizes; (void)n_in; (void)out_size;
  const float* X  = (const float*)d_in[0];
  const int* mask = (const int*)d_in[1];
  float* out = (float*)d_out;

  const size_t szImg = (size_t)Bb * NT * 65536;  // 32 MiB of bf16 images
  if (ws_size >= szImg) {
    unsigned short* W = (unsigned short*)d_ws;
    build_images<<<dim3(NT, Bb), 256, 0, stream>>>(X, W);
    attn_ds2<<<512, 512, 0, stream>>>(W, mask, out);
  } else {
    attn_fb<<<dim3(Nn / 64, Bb), 256, 0, stream>>>(X, mask, out);
  }
}

// Round 19
// 178.410 us; speedup vs baseline: 3.3434x; 3.3434x over previous
//
#include <hip/hip_runtime.h>

#define Bb 8
#define Nn 2048
#define Dd 512

#define KV 32            // keys per tile/image
#define NT 64            // images per batch
#define PPS 40           // sP row stride (u16 elements)

// fallback (no ws): R10 structure
#define KVF 64
#define NTF (Nn / KVF)
#define PPF 72

typedef __attribute__((ext_vector_type(8))) short bf8;
typedef __attribute__((ext_vector_type(4))) float f4;
struct __align__(16) U8 { unsigned short s[8]; };
struct __align__(8) US4 { unsigned short s[4]; };

__device__ __forceinline__ unsigned short f2bf(float f) {
  union { float f; unsigned u; } v; v.f = f;
  unsigned r = v.u + 0x7fffu + ((v.u >> 16) & 1u);
  return (unsigned short)(r >> 16);
}
__device__ __forceinline__ float bf2f(unsigned short h) {
  union { unsigned u; float f; } v; v.u = ((unsigned)h) << 16; return v.f;
}

// async global->LDS, 16B per lane; LDS dest = wave-uniform base + lane*16
__device__ __forceinline__ void gload_lds16(const unsigned short* g, unsigned short* l) {
  __builtin_amdgcn_global_load_lds(
      (const __attribute__((address_space(1))) void*)g,
      (__attribute__((address_space(3))) void*)l, 16, 0, 0);
}

// ---------------------------------------------------------------------------
// Build per-(b,tile) images in ws, once.  Image = [K 16384 | Vt 16384] u16.
//   K : key*512 + ((c ^ (key&7))<<3), c = d>>3        (LDS-swizzled row-major)
//   Vt: 16384 + d*32 + ((g ^ ((d>>1)&3))<<3), g = key>>3  (transpose)
// ---------------------------------------------------------------------------
__global__ __launch_bounds__(256)
void build_images(const float* __restrict__ X, unsigned short* __restrict__ W) {
  __shared__ float sT[KV * Dd];  // 64 KB
  const int t = blockIdx.x, b = blockIdx.y, tid = threadIdx.x;
  const float* src = X + ((size_t)b * Nn + t * KV) * Dd;
#pragma unroll
  for (int i = 0; i < 16; ++i) {
    int idx = i * 256 + tid;
    *(float4*)(sT + idx * 4) = *(const float4*)(src + idx * 4);
  }
  __syncthreads();
  unsigned short* img = W + ((size_t)(b * NT + t) << 15);
#pragma unroll
  for (int i = 0; i < 8; ++i) {
    int idx = i * 256 + tid;
    int key = idx >> 6, c = idx & 63;
    const float* p = sT + key * Dd + c * 8;
    U8 v;
#pragma unroll
    for (int j = 0; j < 8; ++j) v.s[j] = f2bf(p[j]);
    *(U8*)(img + key * 512 + ((c ^ (key & 7)) << 3)) = v;
  }
#pragma unroll
  for (int i = 0; i < 8; ++i) {
    int idx = i * 256 + tid;
    int d = idx >> 2, g = idx & 3;
    U8 v;
#pragma unroll
    for (int e = 0; e < 8; ++e) v.s[e] = f2bf(sT[(g * 8 + e) * Dd + d]);
    *(U8*)(img + 16384 + d * 32 + ((g ^ ((d >> 1) & 3)) << 3)) = v;
  }
}

// ---------------------------------------------------------------------------
// D-half-split attention. 256 thr = 4 waves = 2 qg x 2 dh.
// Wave (qg,dh): 16 q-rows (q0 = qb*32 + qg*16), d-half [dh*256, +256).
//   o[16] f4 = 64 regs + qf[8] = 32 -> ~125 honest VGPR (fits 128 cap of
//   (256,2): no spill). LDS = sK 32 KB + sSx 4 KB + sP 2.5 KB = 39.4 KB
//   -> 2 blocks/CU (256-thr pairing proven at <=~40 KB).
// QK^T partials exchanged via bf16x4 sSx (separate buffer, no extra barrier).
// K staged by global_load_lds (0 VGPRs); V read from L2 Vt image.
// 2 barriers/tile (R18 lesson: every extra barrier ~2.2 us/tile).
// ---------------------------------------------------------------------------
__global__ __launch_bounds__(256, 2)
void attn_dh(const unsigned short* __restrict__ W, const int* __restrict__ mask,
             float* __restrict__ out) {
  __shared__ unsigned short sK[16384];   // 32 KB
  __shared__ US4 sSx[2][2][2][64];       // 4 KB: [qg][dh][cc][slot]
  __shared__ unsigned short sP[2][16 * PPS];  // 2.5 KB

  const int tid  = threadIdx.x;
  const int wave = tid >> 6;
  const int qg = wave >> 1, dh = wave & 1;
  const int lane = tid & 63;
  const int lg = lane >> 4, ll = lane & 15;
  const int slot = lg * 16 + ll;
  const int bid = blockIdx.x;
  const int b = bid & 7;                      // XCD-batch affinity
  const int qb = bid >> 3;                    // 0..63
  const int q0 = qb * 32 + qg * 16;
  const int bN = b * NT;
  const float scale = 0.044194173824159216f;  // 1/sqrt(512)

  // Q fragments for this wave's d-half (from K-images; same addr math as K)
  bf8 qf[8];
  {
    int qrow = q0 + ll;
    const unsigned short* qimg = W + ((size_t)(bN + (qrow >> 5)) << 15);
    int qk = qrow & 31;
#pragma unroll
    for (int ch = 0; ch < 8; ++ch) {
      int c = dh * 32 + ch * 4 + lg;
      qf[ch] = *(const bf8*)(qimg + qk * 512 + ((c ^ (qk & 7)) << 3));
    }
  }

  float bias[4];
#pragma unroll
  for (int r = 0; r < 4; ++r)
    bias[r] = (1.0f - (float)mask[b * Nn + q0 + lg * 4 + r]) * 1e9f;

  float m[4], lsum[4];
  f4 o[16];
#pragma unroll
  for (int r = 0; r < 4; ++r) { m[r] = -1e30f; lsum[r] = 0.0f; }
#pragma unroll
  for (int ct = 0; ct < 16; ++ct) o[ct] = (f4){0.f, 0.f, 0.f, 0.f};

  // prologue: stage K tile 0 via async global->LDS (8 x 1KB per wave)
  {
    const unsigned short* img0 = W + ((size_t)bN << 15);
#pragma unroll
    for (int i = 0; i < 8; ++i) {
      int chunk = i * 4 + wave;  // 0..31, 1 KB each
      gload_lds16(img0 + chunk * 512 + lane * 8, sK + chunk * 512);
    }
  }
  __syncthreads();

  for (int t = 0; t < NT; ++t) {
    // ---- QK^T partial over d-half: 16 MFMAs ----
    f4 s2[2];
    s2[0] = (f4){0.f, 0.f, 0.f, 0.f};
    s2[1] = (f4){0.f, 0.f, 0.f, 0.f};
#pragma unroll
    for (int ch = 0; ch < 8; ++ch) {
#pragma unroll
      for (int cc = 0; cc < 2; ++cc) {
        int key = cc * 16 + ll;
        int c = dh * 32 + ch * 4 + lg;
        bf8 kf = *(const bf8*)(sK + key * 512 + ((c ^ (key & 7)) << 3));
        s2[cc] = __builtin_amdgcn_mfma_f32_16x16x32_bf16(qf[ch], kf, s2[cc], 0, 0, 0);
      }
    }
    // publish partials (bf16x4; separate buffer -> no extra barrier)
#pragma unroll
    for (int cc = 0; cc < 2; ++cc) {
      US4 w;
#pragma unroll
      for (int r = 0; r < 4; ++r) w.s[r] = f2bf(s2[cc][r]);
      sSx[qg][dh][cc][slot] = w;
    }
    __syncthreads();  // barA: sK reads done, partials visible

    // issue next K tile (async, lands by barB's drain)
    if (t + 1 < NT) {
      const unsigned short* gKn = W + ((size_t)(bN + t + 1) << 15);
#pragma unroll
      for (int i = 0; i < 8; ++i) {
        int chunk = i * 4 + wave;
        gload_lds16(gKn + chunk * 512 + lane * 8, sK + chunk * 512);
      }
    }

    // ---- full-D sum (fixed order; identical in both dh waves) ----
    float e2[2][4];
#pragma unroll
    for (int cc = 0; cc < 2; ++cc) {
      US4 lo = sSx[qg][0][cc][slot];
      US4 hi = sSx[qg][1][cc][slot];
#pragma unroll
      for (int r = 0; r < 4; ++r)
        e2[cc][r] = (bf2f(lo.s[r]) + bf2f(hi.s[r])) * scale - bias[r];  // masked -> -1e9
    }

    // ---- online softmax (replicated across dh; identical results) ----
    float tm[4];
#pragma unroll
    for (int r = 0; r < 4; ++r) tm[r] = fmaxf(e2[0][r], e2[1][r]);
#pragma unroll
    for (int off = 1; off < 16; off <<= 1)
#pragma unroll
      for (int r = 0; r < 4; ++r) tm[r] = fmaxf(tm[r], __shfl_xor(tm[r], off));

    float mn[4];
    bool change = false;
#pragma unroll
    for (int r = 0; r < 4; ++r) { mn[r] = fmaxf(m[r], tm[r]); change = change || (mn[r] > m[r]); }
    if (__any(change)) {
#pragma unroll
      for (int r = 0; r < 4; ++r) {
        float al = __expf(m[r] - mn[r]);
        lsum[r] *= al;
        m[r] = mn[r];
#pragma unroll
        for (int ct = 0; ct < 16; ++ct) o[ct][r] *= al;
      }
    }

    float ts[4] = {0.f, 0.f, 0.f, 0.f};
    unsigned short pb[2][4];
#pragma unroll
    for (int cc = 0; cc < 2; ++cc)
#pragma unroll
      for (int r = 0; r < 4; ++r) {
        float p = __expf(e2[cc][r] - m[r]);
        ts[r] += p;
        pb[cc][r] = f2bf(p);
      }
#pragma unroll
    for (int off = 1; off < 16; off <<= 1)
#pragma unroll
      for (int r = 0; r < 4; ++r) ts[r] += __shfl_xor(ts[r], off);
#pragma unroll
    for (int r = 0; r < 4; ++r) lsum[r] += ts[r];

    // ---- shared P (both dh waves write identical bytes; same-wave read) ----
    unsigned short* Pw = sP[qg];
#pragma unroll
    for (int cc = 0; cc < 2; ++cc)
#pragma unroll
      for (int r = 0; r < 4; ++r)
        Pw[(lg * 4 + r) * PPS + cc * 16 + ll] = pb[cc][r];
    bf8 af = *(const bf8*)(Pw + ll * PPS + lg * 8);

    // ---- PV: this wave's d-half of V straight from L2 ----
    const unsigned short* gV = W + ((size_t)(bN + t) << 15) + 16384;
#pragma unroll
    for (int g2 = 0; g2 < 8; ++g2) {
      bf8 va0, va1;
      {
        int d0 = dh * 256 + (g2 * 2) * 16 + ll;
        int d1 = dh * 256 + (g2 * 2 + 1) * 16 + ll;
        va0 = *(const bf8*)(gV + d0 * 32 + ((lg ^ ((d0 >> 1) & 3)) << 3));
        va1 = *(const bf8*)(gV + d1 * 32 + ((lg ^ ((d1 >> 1) & 3)) << 3));
      }
      o[g2 * 2]     = __builtin_amdgcn_mfma_f32_16x16x32_bf16(af, va0, o[g2 * 2], 0, 0, 0);
      o[g2 * 2 + 1] = __builtin_amdgcn_mfma_f32_16x16x32_bf16(af, va1, o[g2 * 2 + 1], 0, 0, 0);
    }
    __syncthreads();  // barB: K loads drained; sSx/sP reads settled
  }

  // ---- epilogue: normalize, store this wave's 16q x 256d block ----
  float inv[4];
#pragma unroll
  for (int r = 0; r < 4; ++r) inv[r] = 1.0f / lsum[r];
#pragma unroll
  for (int ct = 0; ct < 16; ++ct)
#pragma unroll
    for (int r = 0; r < 4; ++r) {
      size_t row = (size_t)b * Nn + q0 + lg * 4 + r;
      out[row * Dd + dh * 256 + ct * 16 + ll] = o[ct][r] * inv[r];
    }
}

// ---------------------------------------------------------------------------
// Fallback (no usable ws): R10 structure, KV=64, in-kernel convert.
// ---------------------------------------------------------------------------
__global__ __launch_bounds__(256, 1)
void attn_fb(const float* __restrict__ Xf, const int* __restrict__ mask,
             float* __restrict__ out) {
  __shared__ unsigned short sKf[KVF * Dd];
  __shared__ unsigned short sVt[Dd * KVF];
  __shared__ unsigned short sPf[4][16 * PPF];

  const int tid  = threadIdx.x;
  const int wave = tid >> 6, lane = tid & 63;
  const int lg = lane >> 4, ll = lane & 15;
  const int b  = blockIdx.y;
  const int q0 = blockIdx.x * 64 + wave * 16;

  bf8 qf[16];
  {
    const size_t qoff = ((size_t)b * Nn + q0 + ll) * Dd;
#pragma unroll
    for (int ch = 0; ch < 16; ++ch) {
      int doff = ch * 32 + lg * 8;
      float4 a = *(const float4*)(Xf + qoff + doff);
      float4 c = *(const float4*)(Xf + qoff + doff + 4);
      bf8 tt;
      tt[0] = (short)f2bf(a.x); tt[1] = (short)f2bf(a.y);
      tt[2] = (short)f2bf(a.z); tt[3] = (short)f2bf(a.w);
      tt[4] = (short)f2bf(c.x); tt[5] = (short)f2bf(c.y);
      tt[6] = (short)f2bf(c.z); tt[7] = (short)f2bf(c.w);
      qf[ch] = tt;
    }
  }
  float bias[4];
#pragma unroll
  for (int r = 0; r < 4; ++r)
    bias[r] = (1.0f - (float)mask[b * Nn + q0 + lg * 4 + r]) * 1e9f;
  float m[4], lsum[4];
  f4 o[32];
#pragma unroll
  for (int r = 0; r < 4; ++r) { m[r] = -1e30f; lsum[r] = 0.0f; }
#pragma unroll
  for (int ct = 0; ct < 32; ++ct) o[ct] = (f4){0.f, 0.f, 0.f, 0.f};
  const float scale = 0.044194173824159216f;

  for (int t = 0; t < NTF; ++t) {
    __syncthreads();
    const size_t base = ((size_t)b * Nn + t * KVF) * Dd;
#pragma unroll
    for (int it = 0; it < 16; ++it) {
      int idx = it * 256 + tid;
      int key = idx >> 6, c = idx & 63;
      const float* sp = Xf + base + key * Dd + c * 8;
      float4 a = *(const float4*)(sp);
      float4 d2 = *(const float4*)(sp + 4);
      U8 v;
      v.s[0] = f2bf(a.x); v.s[1] = f2bf(a.y); v.s[2] = f2bf(a.z); v.s[3] = f2bf(a.w);
      v.s[4] = f2bf(d2.x); v.s[5] = f2bf(d2.y); v.s[6] = f2bf(d2.z); v.s[7] = f2bf(d2.w);
      *(U8*)(sKf + key * 512 + ((c ^ (key & 7)) << 3)) = v;
      int ko = key >> 3, k7 = key & 7;
#pragma unroll
      for (int j = 0; j < 8; ++j) {
        int dd = c * 8 + j;
        sVt[dd * 64 + ((ko ^ j ^ (c & 7)) << 3) + k7] = v.s[j];
      }
    }
    __syncthreads();

    f4 s[4];
#pragma unroll
    for (int cc = 0; cc < 4; ++cc) s[cc] = (f4){0.f, 0.f, 0.f, 0.f};
#pragma unroll
    for (int ch = 0; ch < 16; ++ch)
#pragma unroll
      for (int cc = 0; cc < 4; ++cc) {
        int key = cc * 16 + ll;
        bf8 kf = *(const bf8*)(sKf + key * 512 + (((ch * 4 + lg) ^ (key & 7)) << 3));
        s[cc] = __builtin_amdgcn_mfma_f32_16x16x32_bf16(qf[ch], kf, s[cc], 0, 0, 0);
      }

    float e[4][4];
#pragma unroll
    for (int cc = 0; cc < 4; ++cc)
#pragma unroll
      for (int r = 0; r < 4; ++r) e[cc][r] = s[cc][r] * scale - bias[r];
    float tm[4];
#pragma unroll
    for (int r = 0; r < 4; ++r)
      tm[r] = fmaxf(fmaxf(e[0][r], e[1][r]), fmaxf(e[2][r], e[3][r]));
#pragma unroll
    for (int off = 1; off < 16; off <<= 1)
#pragma unroll
      for (int r = 0; r < 4; ++r) tm[r] = fmaxf(tm[r], __shfl_xor(tm[r], off));
    float mn[4]; bool change = false;
#pragma unroll
    for (int r = 0; r < 4; ++r) { mn[r] = fmaxf(m[r], tm[r]); change = change || (mn[r] > m[r]); }
    if (__any(change)) {
#pragma unroll
      for (int r = 0; r < 4; ++r) {
        float al = __expf(m[r] - mn[r]);
        lsum[r] *= al; m[r] = mn[r];
#pragma unroll
        for (int ct = 0; ct < 32; ++ct) o[ct][r] *= al;
      }
    }
    float ts[4] = {0.f, 0.f, 0.f, 0.f};
    unsigned short pb[4][4];
#pragma unroll
    for (int cc = 0; cc < 4; ++cc)
#pragma unroll
      for (int r = 0; r < 4; ++r) {
        float p = __expf(e[cc][r] - m[r]);
        ts[r] += p; pb[cc][r] = f2bf(p);
      }
#pragma unroll
    for (int off = 1; off < 16; off <<= 1)
#pragma unroll
      for (int r = 0; r < 4; ++r) ts[r] += __shfl_xor(ts[r], off);
#pragma unroll
    for (int r = 0; r < 4; ++r) lsum[r] += ts[r];

    unsigned short* Pw = sPf[wave];
#pragma unroll
    for (int cc = 0; cc < 4; ++cc)
#pragma unroll
      for (int r = 0; r < 4; ++r)
        Pw[(lg * 4 + r) * PPF + cc * 16 + ll] = pb[cc][r];
#pragma unroll
    for (int kc = 0; kc < 2; ++kc) {
      bf8 af = *(const bf8*)(Pw + ll * PPF + kc * 32 + lg * 8);
#pragma unroll
      for (int ct = 0; ct < 32; ++ct) {
        int d = ct * 16 + ll;
        bf8 vf = *(const bf8*)(sVt + d * 64 + (((kc * 4 + lg) ^ (d & 7) ^ ((d >> 3) & 7)) << 3));
        o[ct] = __builtin_amdgcn_mfma_f32_16x16x32_bf16(af, vf, o[ct], 0, 0, 0);
      }
    }
  }
  float inv[4];
#pragma unroll
  for (int r = 0; r < 4; ++r) inv[r] = 1.0f / lsum[r];
#pragma unroll
  for (int ct = 0; ct < 32; ++ct)
#pragma unroll
    for (int r = 0; r < 4; ++r) {
      size_t row = (size_t)b * Nn + q0 + lg * 4 + r;
      out[row * Dd + ct * 16 + ll] = o[ct][r] * inv[r];
    }
}

extern "C" void kernel_launch(void* const* d_in, const int* in_sizes, int n_in,
                              void* d_out, int out_size, void* d_ws, size_t ws_size,
                              hipStream_t stream) {
  (void)in_sizes; (void)n_in; (void)out_size;
  const float* X  = (const float*)d_in[0];
  const int* mask = (const int*)d_in[1];
  float* out = (float*)d_out;

  const size_t szImg = (size_t)Bb * NT * 65536;  // 32 MiB of bf16 images
  if (ws_size >= szImg) {
    unsigned short* W = (unsigned short*)d_ws;
    build_images<<<dim3(NT, Bb), 256, 0, stream>>>(X, W);
    attn_dh<<<512, 256, 0, stream>>>(W, mask, out);
  } else {
    attn_fb<<<dim3(Nn / 64, Bb), 256, 0, stream>>>(X, mask, out);
  }
}